// Round 1
// baseline (2249.277 us; speedup 1.0000x reference)
//
#include <hip/hip_runtime.h>
#include <math.h>

#define DIMC 384
#define NHD  6
#define HD   64
#define WSZ  14
#define NTOK 196
#define NWIN 200
#define NWH  1200
#define MWIN 39200
#define MX   32768
#define MLPD 1536

typedef short short8 __attribute__((ext_vector_type(8)));
typedef float f32x4 __attribute__((ext_vector_type(4)));

__device__ __forceinline__ unsigned short f2bf(float f) {
  unsigned int u = __float_as_uint(f);
  u = (u + 0x7fffu + ((u >> 16) & 1u)) >> 16;
  return (unsigned short)u;
}

// ---------- weight transpose + bf16 convert: out[n*K+k] = bf16(in[k*N+n]) ----------
__global__ void wtrans_kernel(const float* __restrict__ in, unsigned short* __restrict__ out,
                              int K, int N) {
  int id = blockIdx.x * 256 + threadIdx.x;
  if (id >= K * N) return;
  int n = id / K, k = id - n * K;
  out[id] = f2bf(in[(size_t)k * N + n]);
}

// ---------- LN1 + window partition -> bf16 windowed tokens ----------
__global__ __launch_bounds__(64) void ln1win_kernel(const float* __restrict__ x,
    const float* __restrict__ w, const float* __restrict__ b, unsigned short* __restrict__ xw) {
  int t = blockIdx.x;           // windowed token 0..39199
  int lane = threadIdx.x;       // 64
  int win = t / NTOK, p = t - win * NTOK;
  int bb = win / 25, rem = win - bb * 25;
  int wi = rem / 5, wj = rem - wi * 5;
  int i = p / WSZ, j = p - i * WSZ;
  int r = wi * WSZ + i, c = wj * WSZ + j;
  unsigned short* o = xw + (size_t)t * DIMC;
  if (r >= 64 || c >= 64) {     // padded position -> zeros (matches reference pad-after-LN)
    #pragma unroll
    for (int q = 0; q < 6; q++) o[lane + q * 64] = 0;
    return;
  }
  const float* xr = x + (((size_t)bb * 64 + r) * 64 + c) * DIMC;
  float v[6]; float s = 0.f, s2 = 0.f;
  #pragma unroll
  for (int q = 0; q < 6; q++) { float f = xr[lane + q * 64]; v[q] = f; s += f; s2 += f * f; }
  #pragma unroll
  for (int off = 32; off; off >>= 1) { s += __shfl_xor(s, off); s2 += __shfl_xor(s2, off); }
  float mean = s * (1.f / DIMC);
  float var  = s2 * (1.f / DIMC) - mean * mean;
  float rstd = rsqrtf(var + 1e-5f);
  #pragma unroll
  for (int q = 0; q < 6; q++) {
    int d = lane + q * 64;
    o[d] = f2bf((v[q] - mean) * rstd * w[d] + b[d]);
  }
}

// ---------- LN2 ----------
__global__ __launch_bounds__(64) void ln2_kernel(const float* __restrict__ x2,
    const float* __restrict__ w, const float* __restrict__ b, unsigned short* __restrict__ h2) {
  int t = blockIdx.x; int lane = threadIdx.x;
  const float* xr = x2 + (size_t)t * DIMC;
  unsigned short* o = h2 + (size_t)t * DIMC;
  float v[6]; float s = 0.f, s2 = 0.f;
  #pragma unroll
  for (int q = 0; q < 6; q++) { float f = xr[lane + q * 64]; v[q] = f; s += f; s2 += f * f; }
  #pragma unroll
  for (int off = 32; off; off >>= 1) { s += __shfl_xor(s, off); s2 += __shfl_xor(s2, off); }
  float mean = s * (1.f / DIMC);
  float var  = s2 * (1.f / DIMC) - mean * mean;
  float rstd = rsqrtf(var + 1e-5f);
  #pragma unroll
  for (int q = 0; q < 6; q++) {
    int d = lane + q * 64;
    o[d] = f2bf((v[q] - mean) * rstd * w[d] + b[d]);
  }
}

// ---------- bf16 MFMA GEMM: C[M x N] = A[M x K] * WT[N x K]^T, templated epilogue ----------
// EPI 0: qkv   -> scatter fp32 into (3, wh, p, d) + bias
// EPI 1: proj  -> unpartition + bias + residual(x) -> x2 fp32
// EPI 2: fc1   -> bias + exact gelu -> bf16 hidden
// EPI 3: fc2   -> bias + residual(x2) -> d_out fp32
template <int EPI>
__global__ __launch_bounds__(256) void gemm_kernel(
    const unsigned short* __restrict__ A, const unsigned short* __restrict__ WT,
    int Mrows, int Kd,
    const float* __restrict__ bias, const float* __restrict__ addin,
    float* __restrict__ outf, unsigned short* __restrict__ outb) {
  __shared__ unsigned short As[64][40];   // +8 pad for bank spread
  __shared__ unsigned short Bs[64][40];
  const int row0 = blockIdx.x * 64, col0 = blockIdx.y * 64;
  const int tid = threadIdx.x;
  const int lr = tid >> 2, lk = (tid & 3) * 8;
  const int l = tid & 63, wid = tid >> 6;
  const int wr = (wid >> 1) * 32, wc = (wid & 1) * 32;
  const int fr = l & 15, fk = (l >> 4) * 8;
  f32x4 acc[2][2] = {};
  const size_t arow = (size_t)(row0 + lr) * Kd;
  const size_t brow = (size_t)(col0 + lr) * Kd;
  const bool aval = (row0 + lr) < Mrows;
  for (int k0 = 0; k0 < Kd; k0 += 32) {
    int4 av = {0, 0, 0, 0};
    if (aval) av = *(const int4*)(A + arow + k0 + lk);
    *(int4*)&As[lr][lk] = av;
    *(int4*)&Bs[lr][lk] = *(const int4*)(WT + brow + k0 + lk);
    __syncthreads();
    short8 a0 = *(const short8*)&As[wr + fr][fk];
    short8 a1 = *(const short8*)&As[wr + 16 + fr][fk];
    short8 b0 = *(const short8*)&Bs[wc + fr][fk];
    short8 b1 = *(const short8*)&Bs[wc + 16 + fr][fk];
    acc[0][0] = __builtin_amdgcn_mfma_f32_16x16x32_bf16(a0, b0, acc[0][0], 0, 0, 0);
    acc[0][1] = __builtin_amdgcn_mfma_f32_16x16x32_bf16(a0, b1, acc[0][1], 0, 0, 0);
    acc[1][0] = __builtin_amdgcn_mfma_f32_16x16x32_bf16(a1, b0, acc[1][0], 0, 0, 0);
    acc[1][1] = __builtin_amdgcn_mfma_f32_16x16x32_bf16(a1, b1, acc[1][1], 0, 0, 0);
    __syncthreads();
  }
  #pragma unroll
  for (int fi = 0; fi < 2; fi++)
    #pragma unroll
    for (int fj = 0; fj < 2; fj++)
      #pragma unroll
      for (int q = 0; q < 4; q++) {
        int gr = row0 + wr + fi * 16 + (l >> 4) * 4 + q;   // verified C/D: row=(l>>4)*4+reg
        int gc = col0 + wc + fj * 16 + fr;                 //               col=l&15
        if (gr >= Mrows) continue;
        float v = acc[fi][fj][q];
        if (EPI == 0) {
          int sh = col0 >> 6;                 // block covers exactly one (s,h)
          int s = sh / 6, hh = sh - s * 6;
          int d = gc & 63;
          int wv_ = gr / NTOK, p = gr - wv_ * NTOK;
          outf[(((size_t)s * NWH + wv_ * NHD + hh) * NTOK + p) * HD + d] = v + bias[gc];
        } else if (EPI == 1) {
          int wv_ = gr / NTOK, p = gr - wv_ * NTOK;
          int bb = wv_ / 25, rem = wv_ - bb * 25;
          int wi = rem / 5, wj = rem - wi * 5;
          int i = p / WSZ, j = p - i * WSZ;
          int rr = wi * WSZ + i, cc = wj * WSZ + j;
          if (rr < 64 && cc < 64) {
            size_t idx = (((size_t)bb * 64 + rr) * 64 + cc) * DIMC + gc;
            outf[idx] = v + bias[gc] + addin[idx];
          }
        } else if (EPI == 2) {
          float t = v + bias[gc];
          float g = 0.5f * t * (1.f + erff(t * 0.70710678118654752f));
          outb[(size_t)gr * MLPD + gc] = f2bf(g);
        } else {
          size_t idx = (size_t)gr * DIMC + gc;
          outf[idx] = v + bias[gc] + addin[idx];
        }
      }
}

// ---------- attention: one block per (window-head, half of q rows) ----------
__global__ __launch_bounds__(256) void attn_kernel(const float* __restrict__ qkv,
    const float* __restrict__ relh, const float* __restrict__ relw,
    unsigned short* __restrict__ attnout) {
  __shared__ float kT[64 * 212 + 256];     // K transposed [d][kt], padded tail for inactive lanes
  __shared__ float vbuf[196 * 65];         // V row-major [kt][d], stride 65 (conflict-free)
  __shared__ float qs[100 * 64];           // 98 q rows + 2 zero rows
  __shared__ float plds[4][4][200];        // per-wave softmax probs (4 rows)
  __shared__ float rhw[4][4][28];          // per-wave rel-pos dots: [row][0..13]=rh, [14..27]=rw
  const int wh = blockIdx.x, y = blockIdx.y;
  const int w = wh / NHD, h = wh - w * NHD;
  const float* qp = qkv + (size_t)wh * NTOK * HD;
  const float* kp = qp + (size_t)NWH * NTOK * HD;
  const float* vp = kp + (size_t)NWH * NTOK * HD;
  const int tid = threadIdx.x;
  for (int e = tid; e < NTOK * HD; e += 256) {
    int kt = e >> 6, d = e & 63;
    kT[d * 212 + kt] = kp[e];
    vbuf[kt * 65 + d] = vp[e];
  }
  const int qbase = y * 98;
  for (int e = tid; e < 100 * 64; e += 256) {
    int rr = e >> 6;
    qs[e] = (rr < 98) ? qp[(size_t)(qbase + rr) * 64 + (e & 63)] : 0.f;
  }
  __syncthreads();
  const int l = tid & 63, wv = tid >> 6;
  const bool kact = l < 49;                // 49*4 = 196 keys exactly
  const int kt0 = l * 4;
  int khi[4], kwj[4];
  #pragma unroll
  for (int c = 0; c < 4; c++) {
    int kk = kt0 + c; if (kk > 195) kk = 195;
    khi[c] = kk / 14; kwj[c] = kk - khi[c] * 14;
  }
  for (int qb = wv; qb < 25; qb += 4) {    // each wave owns 4-row blocks, stride 4
    const int r0 = qb * 4;
    // phase 1: rel-pos dots (28 lanes: 14 rh + 14 rw per row)
    #pragma unroll
    for (int r = 0; r < 4; r++) {
      if (l < 28) {
        int tok = qbase + r0 + r; if (tok > 195) tok = 195;
        int ii = tok / 14, jj = tok - ii * 14;
        const float* rp = (l < 14) ? (relh + (size_t)(ii - l + 13) * 64)
                                   : (relw + (size_t)(jj - (l - 14) + 13) * 64);
        const float* qrow = &qs[(r0 + r) * 64];
        float sum = 0.f;
        #pragma unroll
        for (int d4 = 0; d4 < 16; d4++) {
          float4 qv = *(const float4*)(qrow + d4 * 4);
          float4 rv = *(const float4*)(rp + d4 * 4);
          sum += qv.x * rv.x + qv.y * rv.y + qv.z * rv.z + qv.w * rv.w;
        }
        rhw[wv][r][l] = sum;
      }
    }
    __builtin_amdgcn_wave_barrier();
    // phase 2: scores, 4 q-rows x 4 keys per lane
    float sc_[4][4] = {{0.f,0.f,0.f,0.f},{0.f,0.f,0.f,0.f},{0.f,0.f,0.f,0.f},{0.f,0.f,0.f,0.f}};
    const float* q0p = &qs[r0 * 64];
    #pragma unroll
    for (int d4 = 0; d4 < 16; d4++) {
      float4 qv[4];
      qv[0] = *(const float4*)(q0p + d4 * 4);
      qv[1] = *(const float4*)(q0p + 64 + d4 * 4);
      qv[2] = *(const float4*)(q0p + 128 + d4 * 4);
      qv[3] = *(const float4*)(q0p + 192 + d4 * 4);
      #pragma unroll
      for (int dd = 0; dd < 4; dd++) {
        float4 kv = *(const float4*)&kT[(d4 * 4 + dd) * 212 + kt0];
        #pragma unroll
        for (int r = 0; r < 4; r++) {
          float qq = dd == 0 ? qv[r].x : dd == 1 ? qv[r].y : dd == 2 ? qv[r].z : qv[r].w;
          sc_[r][0] += qq * kv.x;
          sc_[r][1] += qq * kv.y;
          sc_[r][2] += qq * kv.z;
          sc_[r][3] += qq * kv.w;
        }
      }
    }
    // softmax (wave-parallel)
    float invs[4];
    #pragma unroll
    for (int r = 0; r < 4; r++) {
      float sv[4]; float m = -1e30f;
      #pragma unroll
      for (int c = 0; c < 4; c++) {
        float t = kact ? (sc_[r][c] * 0.125f + rhw[wv][r][khi[c]] + rhw[wv][r][14 + kwj[c]])
                       : -1e30f;
        sv[c] = t; m = fmaxf(m, t);
      }
      #pragma unroll
      for (int off = 32; off; off >>= 1) m = fmaxf(m, __shfl_xor(m, off));
      float sum = 0.f; float pv[4];
      #pragma unroll
      for (int c = 0; c < 4; c++) { float e = kact ? __expf(sv[c] - m) : 0.f; pv[c] = e; sum += e; }
      #pragma unroll
      for (int off = 32; off; off >>= 1) sum += __shfl_xor(sum, off);
      invs[r] = 1.f / sum;
      if (kact) {
        plds[wv][r][kt0]     = pv[0];
        plds[wv][r][kt0 + 1] = pv[1];
        plds[wv][r][kt0 + 2] = pv[2];
        plds[wv][r][kt0 + 3] = pv[3];
      }
    }
    __builtin_amdgcn_wave_barrier();
    // phase 3: out[d=lane] = sum_kt p*V
    float oacc[4] = {0.f, 0.f, 0.f, 0.f};
    for (int kt4 = 0; kt4 < 49; kt4++) {
      float v0 = vbuf[(kt4 * 4 + 0) * 65 + l];
      float v1 = vbuf[(kt4 * 4 + 1) * 65 + l];
      float v2 = vbuf[(kt4 * 4 + 2) * 65 + l];
      float v3 = vbuf[(kt4 * 4 + 3) * 65 + l];
      #pragma unroll
      for (int r = 0; r < 4; r++) {
        float4 pp = *(const float4*)&plds[wv][r][kt4 * 4];
        oacc[r] += pp.x * v0 + pp.y * v1 + pp.z * v2 + pp.w * v3;
      }
    }
    #pragma unroll
    for (int r = 0; r < 4; r++) {
      if (r0 + r < 98) {
        int tok = qbase + r0 + r;
        attnout[((size_t)w * NTOK + tok) * DIMC + h * HD + l] = f2bf(oacc[r] * invs[r]);
      }
    }
  }
}

extern "C" void kernel_launch(void* const* d_in, const int* in_sizes, int n_in,
                              void* d_out, int out_size, void* d_ws, size_t ws_size,
                              hipStream_t stream) {
  const float* x     = (const float*)d_in[0];
  const float* ln1w  = (const float*)d_in[1];
  const float* ln1b  = (const float*)d_in[2];
  const float* qkvw  = (const float*)d_in[3];
  const float* qkvb  = (const float*)d_in[4];
  const float* projw = (const float*)d_in[5];
  const float* projb = (const float*)d_in[6];
  const float* relh  = (const float*)d_in[7];
  const float* relw  = (const float*)d_in[8];
  const float* ln2w  = (const float*)d_in[9];
  const float* ln2b  = (const float*)d_in[10];
  const float* fc1w  = (const float*)d_in[11];
  const float* fc1b  = (const float*)d_in[12];
  const float* fc2w  = (const float*)d_in[13];
  const float* fc2b  = (const float*)d_in[14];

  // workspace regions (buffer reuse):
  // R0: xw bf16 (30.1MB) -> x2 f32 (50.3MB)
  // R1: qkv f32 (180.6MB) -> hidden bf16 (100.7MB)
  // R2: attnout bf16 (30.1MB) -> h2 bf16 (25.2MB)
  // R3: transposed bf16 weights (3.5MB)
  const size_t R0 = 0;
  const size_t R1 = R0 + 50331648;
  const size_t R2 = R1 + 180633600;
  const size_t R3 = R2 + 30105600;
  const size_t NEED = R3 + 3538944;
  if (ws_size < NEED) return;
  char* ws = (char*)d_ws;
  unsigned short* xw     = (unsigned short*)(ws + R0);
  float*          x2     = (float*)(ws + R0);
  float*          qkvbuf = (float*)(ws + R1);
  unsigned short* hidden = (unsigned short*)(ws + R1);
  unsigned short* attno  = (unsigned short*)(ws + R2);
  unsigned short* h2     = (unsigned short*)(ws + R2);
  unsigned short* qkvwT  = (unsigned short*)(ws + R3);
  unsigned short* projwT = qkvwT + 442368;
  unsigned short* fc1wT  = projwT + 147456;
  unsigned short* fc2wT  = fc1wT + 589824;

  wtrans_kernel<<<1728, 256, 0, stream>>>(qkvw, qkvwT, 384, 1152);
  wtrans_kernel<<<576, 256, 0, stream>>>(projw, projwT, 384, 384);
  wtrans_kernel<<<2304, 256, 0, stream>>>(fc1w, fc1wT, 384, 1536);
  wtrans_kernel<<<2304, 256, 0, stream>>>(fc2w, fc2wT, 1536, 384);
  ln1win_kernel<<<MWIN, 64, 0, stream>>>(x, ln1w, ln1b, xw);
  gemm_kernel<0><<<dim3(613, 18), 256, 0, stream>>>(xw, qkvwT, MWIN, 384, qkvb, nullptr, qkvbuf, nullptr);
  attn_kernel<<<dim3(1200, 2), 256, 0, stream>>>(qkvbuf, relh, relw, attno);
  gemm_kernel<1><<<dim3(613, 6), 256, 0, stream>>>(attno, projwT, MWIN, 384, projb, x, x2, nullptr);
  ln2_kernel<<<MX, 64, 0, stream>>>(x2, ln2w, ln2b, h2);
  gemm_kernel<2><<<dim3(512, 24), 256, 0, stream>>>(h2, fc1wT, MX, 384, fc1b, nullptr, nullptr, hidden);
  gemm_kernel<3><<<dim3(512, 6), 256, 0, stream>>>(hidden, fc2wT, MX, 1536, fc2b, x2, (float*)d_out, nullptr);
}

// Round 2
// 564.465 us; speedup vs baseline: 3.9848x; 3.9848x over previous
//
#include <hip/hip_runtime.h>
#include <math.h>

#define DIMC 384
#define NHD  6
#define HD   64
#define WSZ  14
#define NTOK 196
#define NWIN 200
#define NWH  1200
#define MWIN 39200
#define MX   32768
#define MLPD 1536

typedef short short8 __attribute__((ext_vector_type(8)));
typedef float f32x4 __attribute__((ext_vector_type(4)));

__device__ __forceinline__ unsigned short f2bf(float f) {
  unsigned int u = __float_as_uint(f);
  u = (u + 0x7fffu + ((u >> 16) & 1u)) >> 16;
  return (unsigned short)u;
}

// ---------- weight transpose + bf16 convert: out[n*K+k] = bf16(in[k*N+n]) ----------
__global__ void wtrans_kernel(const float* __restrict__ in, unsigned short* __restrict__ out,
                              int K, int N) {
  int id = blockIdx.x * 256 + threadIdx.x;
  if (id >= K * N) return;
  int n = id / K, k = id - n * K;
  out[id] = f2bf(in[(size_t)k * N + n]);
}

// ---------- relcat: [64][64] bf16, rows 0..26 = relh, 27..53 = relw, rest 0 ----------
__global__ void relprep_kernel(const float* __restrict__ relh, const float* __restrict__ relw,
                               unsigned short* __restrict__ relcat) {
  int id = blockIdx.x * 256 + threadIdx.x;
  if (id >= 64 * 64) return;
  int rc = id >> 6, d = id & 63;
  float v = 0.f;
  if (rc < 27) v = relh[rc * 64 + d];
  else if (rc < 54) v = relw[(rc - 27) * 64 + d];
  relcat[id] = f2bf(v);
}

// ---------- LN1 + window partition -> bf16 windowed tokens ----------
__global__ __launch_bounds__(64) void ln1win_kernel(const float* __restrict__ x,
    const float* __restrict__ w, const float* __restrict__ b, unsigned short* __restrict__ xw) {
  int t = blockIdx.x;           // windowed token 0..39199
  int lane = threadIdx.x;       // 64
  int win = t / NTOK, p = t - win * NTOK;
  int bb = win / 25, rem = win - bb * 25;
  int wi = rem / 5, wj = rem - wi * 5;
  int i = p / WSZ, j = p - i * WSZ;
  int r = wi * WSZ + i, c = wj * WSZ + j;
  unsigned short* o = xw + (size_t)t * DIMC;
  if (r >= 64 || c >= 64) {     // padded position -> zeros
    #pragma unroll
    for (int q = 0; q < 6; q++) o[lane + q * 64] = 0;
    return;
  }
  const float* xr = x + (((size_t)bb * 64 + r) * 64 + c) * DIMC;
  float v[6]; float s = 0.f, s2 = 0.f;
  #pragma unroll
  for (int q = 0; q < 6; q++) { float f = xr[lane + q * 64]; v[q] = f; s += f; s2 += f * f; }
  #pragma unroll
  for (int off = 32; off; off >>= 1) { s += __shfl_xor(s, off); s2 += __shfl_xor(s2, off); }
  float mean = s * (1.f / DIMC);
  float var  = s2 * (1.f / DIMC) - mean * mean;
  float rstd = rsqrtf(var + 1e-5f);
  #pragma unroll
  for (int q = 0; q < 6; q++) {
    int d = lane + q * 64;
    o[d] = f2bf((v[q] - mean) * rstd * w[d] + b[d]);
  }
}

// ---------- LN2 ----------
__global__ __launch_bounds__(64) void ln2_kernel(const float* __restrict__ x2,
    const float* __restrict__ w, const float* __restrict__ b, unsigned short* __restrict__ h2) {
  int t = blockIdx.x; int lane = threadIdx.x;
  const float* xr = x2 + (size_t)t * DIMC;
  unsigned short* o = h2 + (size_t)t * DIMC;
  float v[6]; float s = 0.f, s2 = 0.f;
  #pragma unroll
  for (int q = 0; q < 6; q++) { float f = xr[lane + q * 64]; v[q] = f; s += f; s2 += f * f; }
  #pragma unroll
  for (int off = 32; off; off >>= 1) { s += __shfl_xor(s, off); s2 += __shfl_xor(s2, off); }
  float mean = s * (1.f / DIMC);
  float var  = s2 * (1.f / DIMC) - mean * mean;
  float rstd = rsqrtf(var + 1e-5f);
  #pragma unroll
  for (int q = 0; q < 6; q++) {
    int d = lane + q * 64;
    o[d] = f2bf((v[q] - mean) * rstd * w[d] + b[d]);
  }
}

// ---------- bf16 MFMA GEMM: C[M x N] = A[M x K] * WT[N x K]^T, templated epilogue ----------
// EPI 0: qkv  -> bf16 scatter: q,k -> outb[s][wh][196][64]; v -> outb2[wh][64][208] (transposed)
// EPI 1: proj -> unpartition + bias + residual(x) -> x2 fp32
// EPI 2: fc1  -> bias + exact gelu -> bf16 hidden
// EPI 3: fc2  -> bias + residual(x2) -> d_out fp32
template <int EPI>
__global__ __launch_bounds__(256) void gemm_kernel(
    const unsigned short* __restrict__ A, const unsigned short* __restrict__ WT,
    int Mrows, int Kd,
    const float* __restrict__ bias, const float* __restrict__ addin,
    float* __restrict__ outf, unsigned short* __restrict__ outb,
    unsigned short* __restrict__ outb2) {
  __shared__ unsigned short As[64][40];
  __shared__ unsigned short Bs[64][40];
  const int row0 = blockIdx.x * 64, col0 = blockIdx.y * 64;
  const int tid = threadIdx.x;
  const int lr = tid >> 2, lk = (tid & 3) * 8;
  const int l = tid & 63, wid = tid >> 6;
  const int wr = (wid >> 1) * 32, wc = (wid & 1) * 32;
  const int fr = l & 15, fk = (l >> 4) * 8;
  f32x4 acc[2][2] = {};
  const size_t arow = (size_t)(row0 + lr) * Kd;
  const size_t brow = (size_t)(col0 + lr) * Kd;
  const bool aval = (row0 + lr) < Mrows;
  for (int k0 = 0; k0 < Kd; k0 += 32) {
    int4 av = {0, 0, 0, 0};
    if (aval) av = *(const int4*)(A + arow + k0 + lk);
    *(int4*)&As[lr][lk] = av;
    *(int4*)&Bs[lr][lk] = *(const int4*)(WT + brow + k0 + lk);
    __syncthreads();
    short8 a0 = *(const short8*)&As[wr + fr][fk];
    short8 a1 = *(const short8*)&As[wr + 16 + fr][fk];
    short8 b0 = *(const short8*)&Bs[wc + fr][fk];
    short8 b1 = *(const short8*)&Bs[wc + 16 + fr][fk];
    acc[0][0] = __builtin_amdgcn_mfma_f32_16x16x32_bf16(a0, b0, acc[0][0], 0, 0, 0);
    acc[0][1] = __builtin_amdgcn_mfma_f32_16x16x32_bf16(a0, b1, acc[0][1], 0, 0, 0);
    acc[1][0] = __builtin_amdgcn_mfma_f32_16x16x32_bf16(a1, b0, acc[1][0], 0, 0, 0);
    acc[1][1] = __builtin_amdgcn_mfma_f32_16x16x32_bf16(a1, b1, acc[1][1], 0, 0, 0);
    __syncthreads();
  }
  #pragma unroll
  for (int fi = 0; fi < 2; fi++)
    #pragma unroll
    for (int fj = 0; fj < 2; fj++)
      #pragma unroll
      for (int q = 0; q < 4; q++) {
        int gr = row0 + wr + fi * 16 + (l >> 4) * 4 + q;
        int gc = col0 + wc + fj * 16 + fr;
        if (gr >= Mrows) continue;
        float v = acc[fi][fj][q];
        if (EPI == 0) {
          int sh = col0 >> 6;
          int s = sh / 6, hh = sh - s * 6;
          int d = gc & 63;
          int wv_ = gr / NTOK, p = gr - wv_ * NTOK;
          int wh = wv_ * NHD + hh;
          unsigned short val = f2bf(v + bias[gc]);
          if (s < 2) outb[((size_t)s * NWH + wh) * (NTOK * 64) + p * 64 + d] = val;
          else       outb2[((size_t)wh * 64 + d) * 208 + p] = val;
        } else if (EPI == 1) {
          int wv_ = gr / NTOK, p = gr - wv_ * NTOK;
          int bb = wv_ / 25, rem = wv_ - bb * 25;
          int wi = rem / 5, wj = rem - wi * 5;
          int i = p / WSZ, j = p - i * WSZ;
          int rr = wi * WSZ + i, cc = wj * WSZ + j;
          if (rr < 64 && cc < 64) {
            size_t idx = (((size_t)bb * 64 + rr) * 64 + cc) * DIMC + gc;
            outf[idx] = v + bias[gc] + addin[idx];
          }
        } else if (EPI == 2) {
          float t = v + bias[gc];
          float g = 0.5f * t * (1.f + erff(t * 0.70710678118654752f));
          outb[(size_t)gr * MLPD + gc] = f2bf(g);
        } else {
          size_t idx = (size_t)gr * DIMC + gc;
          outf[idx] = v + bias[gc] + addin[idx];
        }
      }
}

// ---------- MFMA attention: one block per window-head, 4 waves, 16-row tiles ----------
// Swapped QK^T (mfma(K,Q)): lane holds q-row = l&15, keys = 16*kt + 4*(l>>4) + reg.
__global__ __launch_bounds__(256) void attn_mfma_kernel(
    const unsigned short* __restrict__ qk_g,   // [2][1200][196][64] bf16
    const unsigned short* __restrict__ vT_g,   // [1200][64][208] bf16
    const unsigned short* __restrict__ relcat, // [64][64] bf16
    unsigned short* __restrict__ attnout) {    // [200*196][384] bf16
  __shared__ __align__(16) unsigned short VT[64][232];    // V^T, keys 196..231 zero
  __shared__ __align__(16) unsigned short P[4][16][232];  // per-wave probs, bf16
  __shared__ __align__(16) float RELB[4][16][68];         // per-wave rel dots
  const int wh = blockIdx.x;
  const int w = wh / NHD, h = wh - w * NHD;
  const int tid = threadIdx.x;
  // stage V^T (coalesced b128 reads from pre-transposed global)
  const unsigned short* vrow = vT_g + (size_t)wh * 64 * 208;
  for (int e = tid; e < 64 * 29; e += 256) {
    int d = e / 29, c = e - d * 29;
    int4 val = {0, 0, 0, 0};
    if (c <= 24) {
      val = *(const int4*)(vrow + d * 208 + c * 8);
      if (c == 24) { val.z = 0; val.w = 0; }   // zero keys 196..199
    }
    *(int4*)&VT[d][c * 8] = val;
  }
  // zero P pad cols 208..223 (once; p-writes cover 0..207 every tile)
  {
    int wv0 = tid >> 6, ll = tid & 63;
    int row = ll >> 2, cb = ll & 3;
    *(int2*)&P[wv0][row][208 + cb * 4] = make_int2(0, 0);
  }
  __syncthreads();
  const int l15 = tid & 15, g = (tid >> 4) & 3, wv = tid >> 6;
  const unsigned short* qg = qk_g + (size_t)wh * (NTOK * 64);
  const unsigned short* kg = qk_g + (size_t)(NWH + wh) * (NTOK * 64);
  for (int tile = wv; tile < 13; tile += 4) {
    const int row0 = tile * 16;
    // Q fragments (B-operand): lane holds Q[row0+l15][32*kk + 8*g .. +7]
    short8 qf[2];
    #pragma unroll
    for (int kk = 0; kk < 2; kk++)
      qf[kk] = *(const short8*)(qg + (size_t)(row0 + l15) * 64 + kk * 32 + g * 8);
    // REL = relcat . Q^T  ->  lane: col=q=l15, row=relcol
    f32x4 ar[4] = {};
    #pragma unroll
    for (int t = 0; t < 4; t++)
      #pragma unroll
      for (int kk = 0; kk < 2; kk++) {
        short8 af = *(const short8*)(relcat + (t * 16 + l15) * 64 + kk * 32 + g * 8);
        ar[t] = __builtin_amdgcn_mfma_f32_16x16x32_bf16(af, qf[kk], ar[t], 0, 0, 0);
      }
    #pragma unroll
    for (int t = 0; t < 4; t++)
      #pragma unroll
      for (int r = 0; r < 4; r++)
        RELB[wv][l15][t * 16 + g * 4 + r] = ar[t][r];
    // S^T = K . Q^T : lane holds scores for q=l15, keys 16kt+4g+r
    f32x4 as_[13] = {};
    #pragma unroll
    for (int kt = 0; kt < 13; kt++)
      #pragma unroll
      for (int kk = 0; kk < 2; kk++) {
        short8 kf = *(const short8*)(kg + (size_t)(kt * 16 + l15) * 64 + kk * 32 + g * 8);
        as_[kt] = __builtin_amdgcn_mfma_f32_16x16x32_bf16(kf, qf[kk], as_[kt], 0, 0, 0);
      }
    // softmax (per-lane 52 values + 4-lane-group reduce)
    int tok = row0 + l15; int tq = tok < 196 ? tok : 195;
    int qi = tq / 14, qj = tq - qi * 14;
    const float* rbh = &RELB[wv][l15][qi + 13];        // rbh[-ki]
    const float* rbw = &RELB[wv][l15][27 + qj + 13];   // rbw[-kj]
    float m = -1e30f;
    #pragma unroll
    for (int kt = 0; kt < 13; kt++)
      #pragma unroll
      for (int r = 0; r < 4; r++) {
        int key = kt * 16 + g * 4 + r;
        int ki = key / 14, kj = key - ki * 14;
        float s = as_[kt][r] * 0.125f + rbh[-ki] + rbw[-kj];
        if (kt == 12) s = (g == 0) ? s : -1e30f;       // keys >= 196 masked
        as_[kt][r] = s; m = fmaxf(m, s);
      }
    m = fmaxf(m, __shfl_xor(m, 16)); m = fmaxf(m, __shfl_xor(m, 32));
    float sum = 0.f;
    #pragma unroll
    for (int kt = 0; kt < 13; kt++)
      #pragma unroll
      for (int r = 0; r < 4; r++) {
        float p = __expf(as_[kt][r] - m);
        as_[kt][r] = p; sum += p;
      }
    sum += __shfl_xor(sum, 16); sum += __shfl_xor(sum, 32);
    float inv = 1.f / sum;
    // normalize + pack bf16 + write P
    #pragma unroll
    for (int kt = 0; kt < 13; kt++) {
      float p0 = as_[kt][0] * inv, p1 = as_[kt][1] * inv;
      float p2 = as_[kt][2] * inv, p3 = as_[kt][3] * inv;
      unsigned int lo, hi;
      asm("v_cvt_pk_bf16_f32 %0, %1, %2" : "=v"(lo) : "v"(p0), "v"(p1));
      asm("v_cvt_pk_bf16_f32 %0, %1, %2" : "=v"(hi) : "v"(p2), "v"(p3));
      *(int2*)&P[wv][l15][kt * 16 + g * 4] = make_int2((int)lo, (int)hi);
    }
    // O = P . V : A-frag from P lds, B-frag from VT lds
    f32x4 ao[4] = {};
    #pragma unroll
    for (int kk = 0; kk < 7; kk++) {
      short8 pa = *(const short8*)&P[wv][l15][kk * 32 + g * 8];
      #pragma unroll
      for (int dt = 0; dt < 4; dt++) {
        short8 vb = *(const short8*)&VT[dt * 16 + l15][kk * 32 + g * 8];
        ao[dt] = __builtin_amdgcn_mfma_f32_16x16x32_bf16(pa, vb, ao[dt], 0, 0, 0);
      }
    }
    // write O: lane holds col=d=16dt+l15, row=q=4g+r
    #pragma unroll
    for (int dt = 0; dt < 4; dt++)
      #pragma unroll
      for (int r = 0; r < 4; r++) {
        int tk = row0 + g * 4 + r;
        if (tk < 196)
          attnout[((size_t)w * NTOK + tk) * DIMC + h * 64 + dt * 16 + l15] = f2bf(ao[dt][r]);
      }
  }
}

extern "C" void kernel_launch(void* const* d_in, const int* in_sizes, int n_in,
                              void* d_out, int out_size, void* d_ws, size_t ws_size,
                              hipStream_t stream) {
  const float* x     = (const float*)d_in[0];
  const float* ln1w  = (const float*)d_in[1];
  const float* ln1b  = (const float*)d_in[2];
  const float* qkvw  = (const float*)d_in[3];
  const float* qkvb  = (const float*)d_in[4];
  const float* projw = (const float*)d_in[5];
  const float* projb = (const float*)d_in[6];
  const float* relh  = (const float*)d_in[7];
  const float* relw  = (const float*)d_in[8];
  const float* ln2w  = (const float*)d_in[9];
  const float* ln2b  = (const float*)d_in[10];
  const float* fc1w  = (const float*)d_in[11];
  const float* fc1b  = (const float*)d_in[12];
  const float* fc2w  = (const float*)d_in[13];
  const float* fc2b  = (const float*)d_in[14];

  // workspace regions:
  // R0: xw bf16 (30.1MB) -> x2 f32 (50.3MB)
  // R1: qk bf16 (60.2MB) + vT bf16 (31.9MB) -> hidden bf16 (100.7MB)
  // R2: attnout bf16 (30.1MB) -> h2 bf16 (25.2MB)
  // R3: transposed bf16 weights + relcat
  const size_t R0 = 0;
  const size_t R1 = R0 + 50331648;
  const size_t R2 = R1 + 100663296;
  const size_t R3 = R2 + 30105600;
  const size_t NEED = R3 + 3547136;
  if (ws_size < NEED) return;
  char* ws = (char*)d_ws;
  unsigned short* xw     = (unsigned short*)(ws + R0);
  float*          x2     = (float*)(ws + R0);
  unsigned short* qk_g   = (unsigned short*)(ws + R1);
  unsigned short* vT_g   = qk_g + (size_t)2 * NWH * NTOK * 64;   // +60,211,200B
  unsigned short* hidden = (unsigned short*)(ws + R1);
  unsigned short* attno  = (unsigned short*)(ws + R2);
  unsigned short* h2     = (unsigned short*)(ws + R2);
  unsigned short* qkvwT  = (unsigned short*)(ws + R3);
  unsigned short* projwT = qkvwT + 442368;
  unsigned short* fc1wT  = projwT + 147456;
  unsigned short* fc2wT  = fc1wT + 589824;
  unsigned short* relcat = fc2wT + 589824;

  wtrans_kernel<<<1728, 256, 0, stream>>>(qkvw, qkvwT, 384, 1152);
  wtrans_kernel<<<576, 256, 0, stream>>>(projw, projwT, 384, 384);
  wtrans_kernel<<<2304, 256, 0, stream>>>(fc1w, fc1wT, 384, 1536);
  wtrans_kernel<<<2304, 256, 0, stream>>>(fc2w, fc2wT, 1536, 384);
  relprep_kernel<<<16, 256, 0, stream>>>(relh, relw, relcat);
  ln1win_kernel<<<MWIN, 64, 0, stream>>>(x, ln1w, ln1b, xw);
  gemm_kernel<0><<<dim3(613, 18), 256, 0, stream>>>(xw, qkvwT, MWIN, 384, qkvb, nullptr, nullptr, qk_g, vT_g);
  attn_mfma_kernel<<<NWH, 256, 0, stream>>>(qk_g, vT_g, relcat, attno);
  gemm_kernel<1><<<dim3(613, 6), 256, 0, stream>>>(attno, projwT, MWIN, 384, projb, x, x2, nullptr, nullptr);
  ln2_kernel<<<MX, 64, 0, stream>>>(x2, ln2w, ln2b, h2);
  gemm_kernel<2><<<dim3(512, 24), 256, 0, stream>>>(h2, fc1wT, MX, 384, fc1b, nullptr, nullptr, hidden, nullptr);
  gemm_kernel<3><<<dim3(512, 6), 256, 0, stream>>>(hidden, fc2wT, MX, 1536, fc2b, x2, (float*)d_out, nullptr, nullptr);
}

// Round 3
// 555.472 us; speedup vs baseline: 4.0493x; 1.0162x over previous
//
#include <hip/hip_runtime.h>
#include <math.h>

#define DIMC 384
#define NHD  6
#define HD   64
#define WSZ  14
#define NTOK 196
#define NWIN 200
#define NWH  1200
#define MWIN 39200
#define MX   32768
#define MLPD 1536

typedef short short8 __attribute__((ext_vector_type(8)));
typedef float f32x4 __attribute__((ext_vector_type(4)));

__device__ __forceinline__ unsigned short f2bf(float f) {
  unsigned int u = __float_as_uint(f);
  u = (u + 0x7fffu + ((u >> 16) & 1u)) >> 16;
  return (unsigned short)u;
}

typedef const __attribute__((address_space(1))) unsigned int* gptr_t;
typedef __attribute__((address_space(3))) unsigned int* lptr_t;
__device__ __forceinline__ void gload16(const unsigned short* g, unsigned short* l) {
  __builtin_amdgcn_global_load_lds((gptr_t)(const void*)g, (lptr_t)(void*)l, 16, 0, 0);
}

// ---------- weight transpose + bf16 convert: out[n*K+k] = bf16(in[k*N+n]) ----------
__global__ void wtrans_kernel(const float* __restrict__ in, unsigned short* __restrict__ out,
                              int K, int N) {
  int id = blockIdx.x * 256 + threadIdx.x;
  if (id >= K * N) return;
  int n = id / K, k = id - n * K;
  out[id] = f2bf(in[(size_t)k * N + n]);
}

// ---------- relcat: [64][64] bf16, rows 0..26 = relh, 27..53 = relw, rest 0 ----------
__global__ void relprep_kernel(const float* __restrict__ relh, const float* __restrict__ relw,
                               unsigned short* __restrict__ relcat) {
  int id = blockIdx.x * 256 + threadIdx.x;
  if (id >= 64 * 64) return;
  int rc = id >> 6, d = id & 63;
  float v = 0.f;
  if (rc < 27) v = relh[rc * 64 + d];
  else if (rc < 54) v = relw[(rc - 27) * 64 + d];
  relcat[id] = f2bf(v);
}

// ---------- LN1 + window partition -> bf16 windowed tokens ----------
__global__ __launch_bounds__(64) void ln1win_kernel(const float* __restrict__ x,
    const float* __restrict__ w, const float* __restrict__ b, unsigned short* __restrict__ xw) {
  int t = blockIdx.x;
  int lane = threadIdx.x;
  int win = t / NTOK, p = t - win * NTOK;
  int bb = win / 25, rem = win - bb * 25;
  int wi = rem / 5, wj = rem - wi * 5;
  int i = p / WSZ, j = p - i * WSZ;
  int r = wi * WSZ + i, c = wj * WSZ + j;
  unsigned short* o = xw + (size_t)t * DIMC;
  if (r >= 64 || c >= 64) {
    #pragma unroll
    for (int q = 0; q < 6; q++) o[lane + q * 64] = 0;
    return;
  }
  const float* xr = x + (((size_t)bb * 64 + r) * 64 + c) * DIMC;
  float v[6]; float s = 0.f, s2 = 0.f;
  #pragma unroll
  for (int q = 0; q < 6; q++) { float f = xr[lane + q * 64]; v[q] = f; s += f; s2 += f * f; }
  #pragma unroll
  for (int off = 32; off; off >>= 1) { s += __shfl_xor(s, off); s2 += __shfl_xor(s2, off); }
  float mean = s * (1.f / DIMC);
  float var  = s2 * (1.f / DIMC) - mean * mean;
  float rstd = rsqrtf(var + 1e-5f);
  #pragma unroll
  for (int q = 0; q < 6; q++) {
    int d = lane + q * 64;
    o[d] = f2bf((v[q] - mean) * rstd * w[d] + b[d]);
  }
}

// ---------- LN2 ----------
__global__ __launch_bounds__(64) void ln2_kernel(const float* __restrict__ x2,
    const float* __restrict__ w, const float* __restrict__ b, unsigned short* __restrict__ h2) {
  int t = blockIdx.x; int lane = threadIdx.x;
  const float* xr = x2 + (size_t)t * DIMC;
  unsigned short* o = h2 + (size_t)t * DIMC;
  float v[6]; float s = 0.f, s2 = 0.f;
  #pragma unroll
  for (int q = 0; q < 6; q++) { float f = xr[lane + q * 64]; v[q] = f; s += f; s2 += f * f; }
  #pragma unroll
  for (int off = 32; off; off >>= 1) { s += __shfl_xor(s, off); s2 += __shfl_xor(s2, off); }
  float mean = s * (1.f / DIMC);
  float var  = s2 * (1.f / DIMC) - mean * mean;
  float rstd = rsqrtf(var + 1e-5f);
  #pragma unroll
  for (int q = 0; q < 6; q++) {
    int d = lane + q * 64;
    o[d] = f2bf((v[q] - mean) * rstd * w[d] + b[d]);
  }
}

// ---------- m97-structure bf16 MFMA GEMM: 128x128 tile, BK=32, global_load_lds ----------
// C[M x N] = A[M x K] * WT[N x K]^T, templated epilogue:
// EPI 0: qkv  -> bf16 scatter: q,k -> outb[s][wh][196][64]; v -> outb2[wh][64][208] (transposed)
// EPI 1: proj -> unpartition + bias + residual(x) -> x2 fp32
// EPI 2: fc1  -> bias + exact gelu -> bf16 hidden
// EPI 3: fc2  -> bias + residual(x2) -> d_out fp32
template <int EPI>
__global__ __launch_bounds__(256) void gemm_kernel(
    const unsigned short* __restrict__ A, const unsigned short* __restrict__ WT,
    int Mrows, int Kd,
    const float* __restrict__ bias, const float* __restrict__ addin,
    float* __restrict__ outf, unsigned short* __restrict__ outb,
    unsigned short* __restrict__ outb2) {
  __shared__ unsigned short As[128 * 32];   // [row][k] linear, row stride 64B
  __shared__ unsigned short Bs[128 * 32];
  const int row0 = blockIdx.x * 128, col0 = blockIdx.y * 128;
  const int tid = threadIdx.x;
  const int l = tid & 63, wid = tid >> 6;
  const int fr = l & 15, fk = (l >> 4) * 8;
  const int wr = (wid >> 1) * 64, wc = (wid & 1) * 64;
  const int sr = l >> 2, sc = (l & 3) * 8;        // staging: 4 lanes x 16B per row
  f32x4 acc[4][4] = {};
  const unsigned short* ap = A + (size_t)row0 * Kd;
  const unsigned short* bp = WT + (size_t)col0 * Kd;
  for (int k0 = 0; k0 < Kd; k0 += 32) {
    #pragma unroll
    for (int j = 0; j < 2; j++) {
      int chunk = j * 4 + wid;                    // 16-row chunk, wave-uniform
      gload16(ap + (size_t)(chunk * 16 + sr) * Kd + k0 + sc, &As[chunk * 512]);
      gload16(bp + (size_t)(chunk * 16 + sr) * Kd + k0 + sc, &Bs[chunk * 512]);
    }
    __syncthreads();                              // compiler drains vmcnt before barrier
    short8 a[4], b[4];
    #pragma unroll
    for (int fi = 0; fi < 4; fi++) {
      a[fi] = *(const short8*)&As[(wr + fi * 16 + fr) * 32 + fk];
      b[fi] = *(const short8*)&Bs[(wc + fi * 16 + fr) * 32 + fk];
    }
    #pragma unroll
    for (int fi = 0; fi < 4; fi++)
      #pragma unroll
      for (int fj = 0; fj < 4; fj++)
        acc[fi][fj] = __builtin_amdgcn_mfma_f32_16x16x32_bf16(a[fi], b[fj], acc[fi][fj], 0, 0, 0);
    __syncthreads();
  }
  #pragma unroll
  for (int fi = 0; fi < 4; fi++)
    #pragma unroll
    for (int fj = 0; fj < 4; fj++)
      #pragma unroll
      for (int q = 0; q < 4; q++) {
        int gr = row0 + wr + fi * 16 + (l >> 4) * 4 + q;
        int gc = col0 + wc + fj * 16 + fr;
        if (gr >= Mrows) continue;
        float v = acc[fi][fj][q];
        if (EPI == 0) {
          int s = gc / 384, rem = gc - s * 384;
          int hh = rem >> 6, d = gc & 63;
          int wv_ = gr / NTOK, p = gr - wv_ * NTOK;
          int wh = wv_ * NHD + hh;
          unsigned short val = f2bf(v + bias[gc]);
          if (s < 2) outb[((size_t)s * NWH + wh) * (NTOK * 64) + p * 64 + d] = val;
          else       outb2[((size_t)wh * 64 + d) * 208 + p] = val;
        } else if (EPI == 1) {
          int wv_ = gr / NTOK, p = gr - wv_ * NTOK;
          int bb = wv_ / 25, rem = wv_ - bb * 25;
          int wi = rem / 5, wj = rem - wi * 5;
          int i = p / WSZ, j = p - i * WSZ;
          int rr = wi * WSZ + i, cc = wj * WSZ + j;
          if (rr < 64 && cc < 64) {
            size_t idx = (((size_t)bb * 64 + rr) * 64 + cc) * DIMC + gc;
            outf[idx] = v + bias[gc] + addin[idx];
          }
        } else if (EPI == 2) {
          float t = v + bias[gc];
          float g = 0.5f * t * (1.f + erff(t * 0.70710678118654752f));
          outb[(size_t)gr * MLPD + gc] = f2bf(g);
        } else {
          size_t idx = (size_t)gr * DIMC + gc;
          outf[idx] = v + bias[gc] + addin[idx];
        }
      }
}

// ---------- MFMA attention: one block per window-head, 4 waves, 16-row tiles ----------
__global__ __launch_bounds__(256) void attn_mfma_kernel(
    const unsigned short* __restrict__ qk_g,   // [2][1200][196][64] bf16
    const unsigned short* __restrict__ vT_g,   // [1200][64][208] bf16
    const unsigned short* __restrict__ relcat, // [64][64] bf16
    unsigned short* __restrict__ attnout) {    // [200*196][384] bf16
  __shared__ __align__(16) unsigned short VT[64][232];
  __shared__ __align__(16) unsigned short P[4][16][232];
  __shared__ __align__(16) float RELB[4][16][68];
  const int wh = blockIdx.x;
  const int w = wh / NHD, h = wh - w * NHD;
  const int tid = threadIdx.x;
  const unsigned short* vrow = vT_g + (size_t)wh * 64 * 208;
  for (int e = tid; e < 64 * 29; e += 256) {
    int d = e / 29, c = e - d * 29;
    int4 val = {0, 0, 0, 0};
    if (c <= 24) {
      val = *(const int4*)(vrow + d * 208 + c * 8);
      if (c == 24) { val.z = 0; val.w = 0; }
    }
    *(int4*)&VT[d][c * 8] = val;
  }
  {
    int wv0 = tid >> 6, ll = tid & 63;
    int row = ll >> 2, cb = ll & 3;
    *(int2*)&P[wv0][row][208 + cb * 4] = make_int2(0, 0);
  }
  __syncthreads();
  const int l15 = tid & 15, g = (tid >> 4) & 3, wv = tid >> 6;
  const unsigned short* qg = qk_g + (size_t)wh * (NTOK * 64);
  const unsigned short* kg = qk_g + (size_t)(NWH + wh) * (NTOK * 64);
  for (int tile = wv; tile < 13; tile += 4) {
    const int row0 = tile * 16;
    short8 qf[2];
    #pragma unroll
    for (int kk = 0; kk < 2; kk++)
      qf[kk] = *(const short8*)(qg + (size_t)(row0 + l15) * 64 + kk * 32 + g * 8);
    f32x4 ar[4] = {};
    #pragma unroll
    for (int t = 0; t < 4; t++)
      #pragma unroll
      for (int kk = 0; kk < 2; kk++) {
        short8 af = *(const short8*)(relcat + (t * 16 + l15) * 64 + kk * 32 + g * 8);
        ar[t] = __builtin_amdgcn_mfma_f32_16x16x32_bf16(af, qf[kk], ar[t], 0, 0, 0);
      }
    #pragma unroll
    for (int t = 0; t < 4; t++)
      #pragma unroll
      for (int r = 0; r < 4; r++)
        RELB[wv][l15][t * 16 + g * 4 + r] = ar[t][r];
    f32x4 as_[13] = {};
    #pragma unroll
    for (int kt = 0; kt < 13; kt++)
      #pragma unroll
      for (int kk = 0; kk < 2; kk++) {
        short8 kf = *(const short8*)(kg + (size_t)(kt * 16 + l15) * 64 + kk * 32 + g * 8);
        as_[kt] = __builtin_amdgcn_mfma_f32_16x16x32_bf16(kf, qf[kk], as_[kt], 0, 0, 0);
      }
    int tok = row0 + l15; int tq = tok < 196 ? tok : 195;
    int qi = tq / 14, qj = tq - qi * 14;
    const float* rbh = &RELB[wv][l15][qi + 13];
    const float* rbw = &RELB[wv][l15][27 + qj + 13];
    float m = -1e30f;
    #pragma unroll
    for (int kt = 0; kt < 13; kt++)
      #pragma unroll
      for (int r = 0; r < 4; r++) {
        int key = kt * 16 + g * 4 + r;
        int ki = key / 14, kj = key - ki * 14;
        float s = as_[kt][r] * 0.125f + rbh[-ki] + rbw[-kj];
        if (kt == 12) s = (g == 0) ? s : -1e30f;
        as_[kt][r] = s; m = fmaxf(m, s);
      }
    m = fmaxf(m, __shfl_xor(m, 16)); m = fmaxf(m, __shfl_xor(m, 32));
    float sum = 0.f;
    #pragma unroll
    for (int kt = 0; kt < 13; kt++)
      #pragma unroll
      for (int r = 0; r < 4; r++) {
        float p = __expf(as_[kt][r] - m);
        as_[kt][r] = p; sum += p;
      }
    sum += __shfl_xor(sum, 16); sum += __shfl_xor(sum, 32);
    float inv = 1.f / sum;
    #pragma unroll
    for (int kt = 0; kt < 13; kt++) {
      float p0 = as_[kt][0] * inv, p1 = as_[kt][1] * inv;
      float p2 = as_[kt][2] * inv, p3 = as_[kt][3] * inv;
      unsigned int lo, hi;
      asm("v_cvt_pk_bf16_f32 %0, %1, %2" : "=v"(lo) : "v"(p0), "v"(p1));
      asm("v_cvt_pk_bf16_f32 %0, %1, %2" : "=v"(hi) : "v"(p2), "v"(p3));
      *(int2*)&P[wv][l15][kt * 16 + g * 4] = make_int2((int)lo, (int)hi);
    }
    f32x4 ao[4] = {};
    #pragma unroll
    for (int kk = 0; kk < 7; kk++) {
      short8 pa = *(const short8*)&P[wv][l15][kk * 32 + g * 8];
      #pragma unroll
      for (int dt = 0; dt < 4; dt++) {
        short8 vb = *(const short8*)&VT[dt * 16 + l15][kk * 32 + g * 8];
        ao[dt] = __builtin_amdgcn_mfma_f32_16x16x32_bf16(pa, vb, ao[dt], 0, 0, 0);
      }
    }
    #pragma unroll
    for (int dt = 0; dt < 4; dt++)
      #pragma unroll
      for (int r = 0; r < 4; r++) {
        int tk = row0 + g * 4 + r;
        if (tk < 196)
          attnout[((size_t)w * NTOK + tk) * DIMC + h * 64 + dt * 16 + l15] = f2bf(ao[dt][r]);
      }
  }
}

extern "C" void kernel_launch(void* const* d_in, const int* in_sizes, int n_in,
                              void* d_out, int out_size, void* d_ws, size_t ws_size,
                              hipStream_t stream) {
  const float* x     = (const float*)d_in[0];
  const float* ln1w  = (const float*)d_in[1];
  const float* ln1b  = (const float*)d_in[2];
  const float* qkvw  = (const float*)d_in[3];
  const float* qkvb  = (const float*)d_in[4];
  const float* projw = (const float*)d_in[5];
  const float* projb = (const float*)d_in[6];
  const float* relh  = (const float*)d_in[7];
  const float* relw  = (const float*)d_in[8];
  const float* ln2w  = (const float*)d_in[9];
  const float* ln2b  = (const float*)d_in[10];
  const float* fc1w  = (const float*)d_in[11];
  const float* fc1b  = (const float*)d_in[12];
  const float* fc2w  = (const float*)d_in[13];
  const float* fc2b  = (const float*)d_in[14];

  // workspace regions:
  // R0: xw bf16 (30.1MB) -> x2 f32 (50.3MB)
  // R1: qk bf16 (60.2MB) + vT bf16 (31.9MB) -> hidden bf16 (100.7MB)
  // R2: attnout bf16 (30.1MB) -> h2 bf16 (25.2MB)
  // R3: transposed bf16 weights + relcat
  const size_t R0 = 0;
  const size_t R1 = R0 + 50331648;
  const size_t R2 = R1 + 100663296;
  const size_t R3 = R2 + 30105600;
  const size_t NEED = R3 + 3547136;
  if (ws_size < NEED) return;
  char* ws = (char*)d_ws;
  unsigned short* xw     = (unsigned short*)(ws + R0);
  float*          x2     = (float*)(ws + R0);
  unsigned short* qk_g   = (unsigned short*)(ws + R1);
  unsigned short* vT_g   = qk_g + (size_t)2 * NWH * NTOK * 64;
  unsigned short* hidden = (unsigned short*)(ws + R1);
  unsigned short* attno  = (unsigned short*)(ws + R2);
  unsigned short* h2     = (unsigned short*)(ws + R2);
  unsigned short* qkvwT  = (unsigned short*)(ws + R3);
  unsigned short* projwT = qkvwT + 442368;
  unsigned short* fc1wT  = projwT + 147456;
  unsigned short* fc2wT  = fc1wT + 589824;
  unsigned short* relcat = fc2wT + 589824;

  wtrans_kernel<<<1728, 256, 0, stream>>>(qkvw, qkvwT, 384, 1152);
  wtrans_kernel<<<576, 256, 0, stream>>>(projw, projwT, 384, 384);
  wtrans_kernel<<<2304, 256, 0, stream>>>(fc1w, fc1wT, 384, 1536);
  wtrans_kernel<<<2304, 256, 0, stream>>>(fc2w, fc2wT, 1536, 384);
  relprep_kernel<<<16, 256, 0, stream>>>(relh, relw, relcat);
  ln1win_kernel<<<MWIN, 64, 0, stream>>>(x, ln1w, ln1b, xw);
  gemm_kernel<0><<<dim3(307, 9), 256, 0, stream>>>(xw, qkvwT, MWIN, 384, qkvb, nullptr, nullptr, qk_g, vT_g);
  attn_mfma_kernel<<<NWH, 256, 0, stream>>>(qk_g, vT_g, relcat, attno);
  gemm_kernel<1><<<dim3(307, 3), 256, 0, stream>>>(attno, projwT, MWIN, 384, projb, x, x2, nullptr, nullptr);
  ln2_kernel<<<MX, 64, 0, stream>>>(x2, ln2w, ln2b, h2);
  gemm_kernel<2><<<dim3(256, 12), 256, 0, stream>>>(h2, fc1wT, MX, 384, fc1b, nullptr, nullptr, hidden, nullptr);
  gemm_kernel<3><<<dim3(256, 3), 256, 0, stream>>>(hidden, fc2wT, MX, 1536, fc2b, x2, (float*)d_out, nullptr, nullptr);
}